// Round 14
// baseline (19302.763 us; speedup 1.0000x reference)
//
#include <hip/hip_runtime.h>
#include <math.h>

// Problem constants (fixed by the reference)
#define B_  32
#define C_  64
#define T_  2048
#define H_  1024

// Recurrence decomposition: 16 groups x 2 batches; 16 WGs (slices) per group
// R6-proven spread mapping: g = wg>>4 (each group's 16 WGs round-robin over
// all 8 XCDs -> atomic RMWs parallelize across 8 TCCs; XCD-pure serializes
// one TCC and is 2.8x slower, R12).
#define NGROUP 16
#define BPG    2
#define NSLICE 16
#define ROWS   64                    // H / NSLICE
#define NWG    (NGROUP * NSLICE)     // 256 WGs == 256 CUs -> co-resident
#define NTHR   512
#define CHUNK  66                    // padded LDS chunk stride (conflicts ~ 0)

// d_ws layout:
//   [0, 4096)          : unsigned cnt[1024]; group g's barrier counter at
//                        cnt[g*32] (128B apart). cnt[512] = sink dump (unused)
//   [4096, 4096+256KB) : float hbuf[2][B_][H_] (dense ping-pong h exchange)

__global__ void esn_init_kernel(unsigned* cnt, unsigned* hbuf32) {
    int i = blockIdx.x * blockDim.x + threadIdx.x;
    if (i < 1024) cnt[i] = 0u;
    hbuf32[i] = 0u;   // grid 256x256 = 65536 = 2*B_*H_
}

// ---------------------------------------------------------------------------
// x_proj[b,h,t] = bias[h] + sum_c x[b,c,t] * W_in[h,c] -> d_out (B,H,T)
// ---------------------------------------------------------------------------
__global__ __launch_bounds__(256) void esn_xproj_kernel(
        const float* __restrict__ x,
        const float* __restrict__ W_in,
        const float* __restrict__ bias,
        float* __restrict__ out) {
    __shared__ float xs[32 * 256];
    const int tid = threadIdx.x;
    const int t0  = blockIdx.x * 256;
    const int h0  = blockIdx.y * 8;
    const int b   = blockIdx.z;
    const float* xb = x + (size_t)b * C_ * T_ + t0;

    float acc[8];
#pragma unroll
    for (int h = 0; h < 8; ++h) acc[h] = 0.0f;

    for (int ch = 0; ch < 2; ++ch) {
        for (int idx = tid; idx < 32 * 64; idx += 256) {
            const int c  = idx >> 6;
            const int t4 = idx & 63;
            float4 v = *(const float4*)(xb + (size_t)(ch * 32 + c) * T_ + t4 * 4);
            *(float4*)(&xs[c * 256 + t4 * 4]) = v;
        }
        __syncthreads();
        for (int c = 0; c < 32; ++c) {
            const float xv = xs[c * 256 + tid];
#pragma unroll
            for (int h = 0; h < 8; ++h)
                acc[h] = fmaf(xv, W_in[(size_t)(h0 + h) * C_ + ch * 32 + c], acc[h]);
        }
        __syncthreads();
    }

    float* ob = out + (size_t)b * H_ * T_ + t0 + tid;
#pragma unroll
    for (int h = 0; h < 8; ++h)
        ob[(size_t)(h0 + h) * T_] = acc[h] + bias[h0 + h];
}

// ---------------------------------------------------------------------------
// Recurrence: R6 protocol exactly (ALL cross-WG data via relaxed AGENT-scope
// atomic RMWs — reads fetch_add(+0), writes returning-exchange, central
// monotone RMW barrier; the ONLY HW-proven-correct-and-fast exchange after
// 13 rounds of elimination), plus round-14 split-half pipelining:
//   read+stage half A -> sync -> ISSUE half-B RMW (unused) -> compute A's
//   128 FMAs while B is in flight -> stage B -> sync -> compute B.
// Thread weight layout matches: w[k<8] = cols cg*32+[0,32) (half A),
// w[k>=8] = cols 512+cg*32+[0,32) (half B); row dot still reduces over the
// 16 cg lanes. Finalize issues the h-exchange BEFORE the out stores.
// Weights live in registers across the t-loop (no __restrict__ anywhere ->
// in-loop reload illegal under possible aliasing with the stores).
// ---------------------------------------------------------------------------
__global__ __launch_bounds__(NTHR, 2) void esn_recur_kernel(
        const float* W_res,
        float* out,
        unsigned* cnt,
        float* hbuf) {
    const int wg   = blockIdx.x;
    const int g    = wg >> 4;                   // spread groups (R6 mapping)
    const int s    = wg & 15;
    const int tid  = threadIdx.x;
    const int wave = tid >> 6;
    const int lane = tid & 63;
    const int cg   = lane & 15;                 // col-group
    const int rt   = (wave << 2) + (lane >> 4); // 0..31 row-pair index
    const int row0 = s * ROWS + rt * 2;
    const int b0   = g * BPG;

    unsigned long long* hb64 = (unsigned long long*)hbuf;
    unsigned* grpcnt = &cnt[g * 32];
    unsigned long long sink = 0ull;

    // ---- persistent register weights: 2 rows x (8 A + 8 B) float4 ----
    float4 w0[16], w1[16];
    {
        const float* wr0 = W_res + (size_t)row0 * H_;
        const float* wr1 = wr0 + H_;
        const int colA = cg * 32;
        const int colB = 512 + cg * 32;
#pragma unroll
        for (int k = 0; k < 8; ++k) {
            w0[k]     = *(const float4*)(wr0 + colA + 4 * k);
            w0[k + 8] = *(const float4*)(wr0 + colB + 4 * k);
            w1[k]     = *(const float4*)(wr1 + colA + 4 * k);
            w1[k + 8] = *(const float4*)(wr1 + colB + 4 * k);
        }
    }

    // h tiles in LDS: batch b, half h, chunk c(0..7), offset o(0..63)
    //   index = h*8*CHUNK + c*CHUNK + o
    __shared__ __align__(16) float hl[BPG][16 * CHUNK];

    // h-fill role: thread loads 2 consecutive h floats per half (1 u64 RMW)
    const int fb = tid >> 8;                 // batch 0/1
    const int ci = (tid & 255) << 1;         // col base within half (even)
    float* hlwA = &hl[fb][(ci >> 6) * CHUNK + (ci & 63)];
    float* hlwB = hlwA + 8 * CHUNK;

    // compute-read bases (32 contiguous floats per half per batch)
    const float* hA0 = &hl[0][(cg >> 1) * CHUNK + (cg & 1) * 32];
    const float* hA1 = &hl[1][(cg >> 1) * CHUNK + (cg & 1) * 32];

    // finalize role: lanes cg<2 own batch b0+cg, rows (row0, row0+1)
    const bool fin  = (cg < BPG);
    const int  fbat = cg;                    // 0/1 (valid when fin)
    float* op0 = out + ((size_t)(b0 + (fin ? fbat : 0)) * H_ + row0) * (size_t)T_;
    float* op1 = op0 + T_;                   // next row, same batch

    float xp0 = fin ? op0[0] : 0.0f;         // x_proj for step 0
    float xp1 = fin ? op1[0] : 0.0f;
    float hprev0 = 0.0f, hprev1 = 0.0f;      // own rows' exact f32 state

    for (int t = 0; t < T_; ++t) {
        const int p = t & 1;
        const size_t plane = (size_t)(p * B_ + b0 + fb) * H_;

        // (A) read + stage half A (1 u64 RMW -> LDS)
        {
            unsigned long long qA = __hip_atomic_fetch_add(
                hb64 + ((plane + ci) >> 1), 0ull,
                __ATOMIC_RELAXED, __HIP_MEMORY_SCOPE_AGENT);
            *(float2*)hlwA = make_float2(__uint_as_float((unsigned)qA),
                                         __uint_as_float((unsigned)(qA >> 32)));
        }
        __syncthreads();
        __builtin_amdgcn_sched_barrier(0);

        // (B1) issue half-B read; result not used until after compute-A,
        // so its TCC serialization overlaps the A-FMAs below.
        unsigned long long qB = __hip_atomic_fetch_add(
            hb64 + ((plane + 512 + ci) >> 1), 0ull,
            __ATOMIC_RELAXED, __HIP_MEMORY_SCOPE_AGENT);

        // prefetch next step's x_proj (plain cached; overlaps compute)
        float xp0n = 0.0f, xp1n = 0.0f;
        if (fin && t + 1 < T_) { xp0n = op0[t + 1]; xp1n = op1[t + 1]; }

        // (C1) compute half A: 2 rows x 32 cols x 2 batches
        float s00 = 0.f, s01 = 0.f, s10 = 0.f, s11 = 0.f;  // s[row][batch]
#pragma unroll
        for (int k = 0; k < 8; ++k) {
            const float4 ha  = *(const float4*)(hA0 + 4 * k);
            const float4 hb4 = *(const float4*)(hA1 + 4 * k);
            const float4 u = w0[k], v = w1[k];
            s00 = fmaf(u.x, ha.x, s00);  s00 = fmaf(u.y, ha.y, s00);
            s00 = fmaf(u.z, ha.z, s00);  s00 = fmaf(u.w, ha.w, s00);
            s10 = fmaf(v.x, ha.x, s10);  s10 = fmaf(v.y, ha.y, s10);
            s10 = fmaf(v.z, ha.z, s10);  s10 = fmaf(v.w, ha.w, s10);
            s01 = fmaf(u.x, hb4.x, s01); s01 = fmaf(u.y, hb4.y, s01);
            s01 = fmaf(u.z, hb4.z, s01); s01 = fmaf(u.w, hb4.w, s01);
            s11 = fmaf(v.x, hb4.x, s11); s11 = fmaf(v.y, hb4.y, s11);
            s11 = fmaf(v.w, hb4.w, s11); s11 = fmaf(v.z, hb4.z, s11);
        }

        // (B2) stage half B (first use of qB -> waitcnt lands here)
        *(float2*)hlwB = make_float2(__uint_as_float((unsigned)qB),
                                     __uint_as_float((unsigned)(qB >> 32)));
        __syncthreads();
        __builtin_amdgcn_sched_barrier(0);

        // (C2) compute half B
#pragma unroll
        for (int k = 0; k < 8; ++k) {
            const float4 ha  = *(const float4*)(hA0 + 8 * CHUNK + 4 * k);
            const float4 hb4 = *(const float4*)(hA1 + 8 * CHUNK + 4 * k);
            const float4 u = w0[k + 8], v = w1[k + 8];
            s00 = fmaf(u.x, ha.x, s00);  s00 = fmaf(u.y, ha.y, s00);
            s00 = fmaf(u.z, ha.z, s00);  s00 = fmaf(u.w, ha.w, s00);
            s10 = fmaf(v.x, ha.x, s10);  s10 = fmaf(v.y, ha.y, s10);
            s10 = fmaf(v.z, ha.z, s10);  s10 = fmaf(v.w, ha.w, s10);
            s01 = fmaf(u.x, hb4.x, s01); s01 = fmaf(u.y, hb4.y, s01);
            s01 = fmaf(u.z, hb4.z, s01); s01 = fmaf(u.w, hb4.w, s01);
            s11 = fmaf(v.x, hb4.x, s11); s11 = fmaf(v.y, hb4.y, s11);
            s11 = fmaf(v.z, hb4.z, s11); s11 = fmaf(v.w, hb4.w, s11);
        }

        // (D) reduce over the 16 cg lanes
#pragma unroll
        for (int m = 1; m <= 8; m <<= 1) {
            s00 += __shfl_xor(s00, m);
            s01 += __shfl_xor(s01, m);
            s10 += __shfl_xor(s10, m);
            s11 += __shfl_xor(s11, m);
        }

        // (E) finalize: lane cg owns batch b0+cg, rows row0 & row0+1.
        //     h-exchange FIRST (peers unblock earliest), out stores after.
        if (fin) {
            const float sA = fbat ? s01 : s00;   // row0
            const float sB = fbat ? s11 : s10;   // row0+1
            const float pre0 = tanhf(xp0 + sA);
            const float pre1 = tanhf(xp1 + sB);
            const float hn0 = fmaf(0.1f, hprev0, 0.9f * pre0);
            const float hn1 = fmaf(0.1f, hprev1, 0.9f * pre1);
            hprev0 = hn0;
            hprev1 = hn1;
            const unsigned long long pack =
                ((unsigned long long)__float_as_uint(hn1) << 32) |
                (unsigned long long)__float_as_uint(hn0);
            const size_t w64 =
                (((size_t)(((t + 1) & 1) * B_ + b0 + fbat) * H_) + row0) >> 1;
            sink ^= __hip_atomic_exchange(hb64 + w64, pack,
                                          __ATOMIC_RELAXED,
                                          __HIP_MEMORY_SCOPE_AGENT);
            op0[t] = hn0;                         // plain cached output stores
            op1[t] = hn1;
        }
        xp0 = xp0n;
        xp1 = xp1n;

        // (F) group barrier: monotone agent-RMW counter (R6-proven)
        if (t + 1 < T_) {
            __syncthreads();   // vmcnt(0): all swaps executed
            __builtin_amdgcn_sched_barrier(0);
            if (tid == 0) {
                __hip_atomic_fetch_add(grpcnt, 1u, __ATOMIC_RELAXED,
                                       __HIP_MEMORY_SCOPE_AGENT);
                const unsigned tgt = (unsigned)NSLICE * (unsigned)(t + 1);
                while (__hip_atomic_fetch_add(grpcnt, 0u, __ATOMIC_RELAXED,
                                              __HIP_MEMORY_SCOPE_AGENT) < tgt) {
                    __builtin_amdgcn_s_sleep(1);
                }
            }
            __syncthreads();
            __builtin_amdgcn_sched_barrier(0);
        }
    }

    // keep the swap returns live (forces the returning/sc0 form)
    if (sink == 0x9E3779B97F4A7C15ull && tid == 0) cnt[512] = 1u;
}

extern "C" void kernel_launch(void* const* d_in, const int* in_sizes, int n_in,
                              void* d_out, int out_size, void* d_ws, size_t ws_size,
                              hipStream_t stream) {
    const float* x     = (const float*)d_in[0];   // (B, C, T)
    const float* W_in  = (const float*)d_in[1];   // (H, C)
    const float* W_res = (const float*)d_in[2];   // (H, H)
    const float* bias  = (const float*)d_in[3];   // (H,)
    float* out = (float*)d_out;                   // (B, H, T)

    unsigned* cnt  = (unsigned*)d_ws;
    float*    hbuf = (float*)((char*)d_ws + 4096);

    esn_init_kernel<<<256, 256, 0, stream>>>(cnt, (unsigned*)hbuf);

    dim3 g1(T_ / 256, H_ / 8, B_);
    esn_xproj_kernel<<<g1, 256, 0, stream>>>(x, W_in, bias, out);

    esn_recur_kernel<<<NWG, NTHR, 0, stream>>>(W_res, out, cnt, hbuf);
}